// Round 1
// baseline (230.044 us; speedup 1.0000x reference)
//
#include <hip/hip_runtime.h>

// SNN_60567628808223: 2-layer LIF SNN.
//   inputs: data[16384,784] f32, W1[128,784], b1[128], W2[10,128], b2[10]
//   output: spk2 [50,16384,10] f32 (binary 0/1)
// Phase A: cur1 = data @ W1^T + b1  -> d_ws   (fp32 SGEMM, vector ALU)
// Phase B: 50-step fused time loop (no barriers, butterfly shuffle reduce)

#define TSTEPS 50
#define NB 16384
#define ND 784
#define NH 128
#define NO 10

#define BK 16
#define LDT 68   // padded LDS leading stride (floats): 16B-aligned, <=2-way bank conflict

__global__ __launch_bounds__(256, 2)
void gemm_cur1(const float* __restrict__ data, const float* __restrict__ W1,
               const float* __restrict__ b1, float* __restrict__ cur1)
{
    // BM=64 rows, BN=64 cols, BK=16; grid = (16384/64)*(128/64) = 512 blocks
    __shared__ float As[BK * LDT];
    __shared__ float Ws[BK * LDT];

    const int tid  = threadIdx.x;
    const int bx   = blockIdx.x;
    const int bm   = bx >> 1;
    const int bn   = bx & 1;
    const int row0 = bm * 64;
    const int col0 = bn * 64;

    // staging assignment: thread loads one float4 along K
    const int lm = tid >> 2;        // 0..63 (row within tile)
    const int lk = (tid & 3) * 4;   // 0,4,8,12 (k offset)

    const float* aSrc = data + (size_t)(row0 + lm) * ND + lk;
    const float* wSrc = W1   + (size_t)(col0 + lm) * ND + lk;

    const int tx = tid & 15;   // 16 col groups * 4 cols
    const int ty = tid >> 4;   // 16 row groups * 4 rows

    float4 aReg = *(const float4*)aSrc;
    float4 wReg = *(const float4*)wSrc;

    float acc[4][4] = {};

    for (int c = 0; c < 49; ++c) {
        __syncthreads();
        // write staged regs transposed: As[k][m], Ws[k][n]
        As[(lk + 0) * LDT + lm] = aReg.x;
        As[(lk + 1) * LDT + lm] = aReg.y;
        As[(lk + 2) * LDT + lm] = aReg.z;
        As[(lk + 3) * LDT + lm] = aReg.w;
        Ws[(lk + 0) * LDT + lm] = wReg.x;
        Ws[(lk + 1) * LDT + lm] = wReg.y;
        Ws[(lk + 2) * LDT + lm] = wReg.z;
        Ws[(lk + 3) * LDT + lm] = wReg.w;
        __syncthreads();
        if (c < 48) {   // prefetch next chunk into registers (overlaps compute)
            aReg = *(const float4*)(aSrc + (c + 1) * BK);
            wReg = *(const float4*)(wSrc + (c + 1) * BK);
        }
        #pragma unroll
        for (int k = 0; k < BK; ++k) {
            float4 a4 = *(const float4*)&As[k * LDT + ty * 4];
            float4 b4 = *(const float4*)&Ws[k * LDT + tx * 4];
            float av[4] = {a4.x, a4.y, a4.z, a4.w};
            float bv[4] = {b4.x, b4.y, b4.z, b4.w};
            #pragma unroll
            for (int i = 0; i < 4; ++i)
                #pragma unroll
                for (int j = 0; j < 4; ++j)
                    acc[i][j] = fmaf(av[i], bv[j], acc[i][j]);
        }
    }

    float4 bv1 = *(const float4*)&b1[col0 + tx * 4];
    #pragma unroll
    for (int i = 0; i < 4; ++i) {
        float4 o;
        o.x = acc[i][0] + bv1.x;
        o.y = acc[i][1] + bv1.y;
        o.z = acc[i][2] + bv1.z;
        o.w = acc[i][3] + bv1.w;
        *(float4*)&cur1[(size_t)(row0 + ty * 4 + i) * NH + col0 + tx * 4] = o;
    }
}

// Fused 50-step time loop. 16 lanes per batch row (8 h-values each),
// 16 rows per 256-thread block -> grid = 1024 blocks. No LDS, no barriers.
__global__ void snn_loop(const float* __restrict__ cur1,
                         const float* __restrict__ W2,
                         const float* __restrict__ b2,
                         float* __restrict__ out)
{
    const int tid = threadIdx.x;
    const int hg  = tid & 15;                  // h-group (also output index o for hg<10)
    const int rl  = tid >> 4;                  // row within block
    const int row = blockIdx.x * 16 + rl;
    const int h0  = hg * 8;

    // W2 fragment in registers: w2[o][j] for this lane's 8 h-values
    float w2[10][8];
    #pragma unroll
    for (int o = 0; o < 10; ++o) {
        float4 u = *(const float4*)&W2[o * NH + h0];
        float4 v = *(const float4*)&W2[o * NH + h0 + 4];
        w2[o][0] = u.x; w2[o][1] = u.y; w2[o][2] = u.z; w2[o][3] = u.w;
        w2[o][4] = v.x; w2[o][5] = v.y; w2[o][6] = v.z; w2[o][7] = v.w;
    }
    const float b2r = b2[hg < 10 ? hg : 0];

    float c[8];
    {
        float4 c0 = *(const float4*)&cur1[(size_t)row * NH + h0];
        float4 c1 = *(const float4*)&cur1[(size_t)row * NH + h0 + 4];
        c[0] = c0.x; c[1] = c0.y; c[2] = c0.z; c[3] = c0.w;
        c[4] = c1.x; c[5] = c1.y; c[6] = c1.z; c[7] = c1.w;
    }

    float mem1[8], spk1[8];
    #pragma unroll
    for (int j = 0; j < 8; ++j) { mem1[j] = 0.f; spk1[j] = 0.f; }
    float mem2 = 0.f, spk2 = 0.f;   // lane hg owns output index o = hg (hg<10)

    for (int t = 0; t < TSTEPS; ++t) {
        // layer 1: mem = beta*mem + c - rst   (rst == previous spike, thr=1)
        #pragma unroll
        for (int j = 0; j < 8; ++j) {
            float m = __fadd_rn(__fmul_rn(0.9f, mem1[j]), c[j]);
            m = __fsub_rn(m, spk1[j]);
            mem1[j] = m;
            spk1[j] = (m > 1.0f) ? 1.0f : 0.0f;
        }
        // partial dot: p[o] = sum_j spk1[j] * W2[o][h0+j]
        float p[10];
        #pragma unroll
        for (int o = 0; o < 10; ++o) p[o] = 0.f;
        #pragma unroll
        for (int j = 0; j < 8; ++j)
            #pragma unroll
            for (int o = 0; o < 10; ++o)
                p[o] = fmaf(spk1[j], w2[o][j], p[o]);
        // butterfly reduce across the 16 lanes of this row
        #pragma unroll
        for (int m = 1; m <= 8; m <<= 1)
            #pragma unroll
            for (int o = 0; o < 10; ++o)
                p[o] += __shfl_xor(p[o], m, 64);
        // lane hg extracts p[hg] (unrolled select; hg is loop-invariant)
        float tot = p[0];
        #pragma unroll
        for (int o = 1; o < 10; ++o)
            tot = (hg == o) ? p[o] : tot;
        // layer 2 update (lane owns one output neuron)
        float cur2 = __fadd_rn(tot, b2r);
        float m2 = __fsub_rn(__fadd_rn(__fmul_rn(0.9f, mem2), cur2), spk2);
        mem2 = m2;
        spk2 = (m2 > 1.0f) ? 1.0f : 0.0f;
        if (hg < 10)
            out[(size_t)t * (NB * NO) + row * NO + hg] = spk2;
    }
}

extern "C" void kernel_launch(void* const* d_in, const int* in_sizes, int n_in,
                              void* d_out, int out_size, void* d_ws, size_t ws_size,
                              hipStream_t stream) {
    const float* data = (const float*)d_in[0];
    const float* W1   = (const float*)d_in[1];
    const float* b1   = (const float*)d_in[2];
    const float* W2   = (const float*)d_in[3];
    const float* b2   = (const float*)d_in[4];
    float* out  = (float*)d_out;
    float* cur1 = (float*)d_ws;   // 16384*128*4 = 8.4 MB scratch

    gemm_cur1<<<512, 256, 0, stream>>>(data, W1, b1, cur1);
    snn_loop<<<1024, 256, 0, stream>>>(cur1, W2, b2, out);
}